// Round 4
// baseline (66.978 us; speedup 1.0000x reference)
//
#include <hip/hip_runtime.h>
#include <hip/hip_bf16.h>

#define NB 8
#define SEQ 2048
#define DIN 1024
#define DH 64

typedef __attribute__((ext_vector_type(8))) short bf16x8;
typedef __attribute__((ext_vector_type(4))) float f32x4;

static __device__ __forceinline__ unsigned short f2bf(float f) {
    unsigned int u = __builtin_bit_cast(unsigned int, f);
    unsigned int r = (u + 0x7FFFu + ((u >> 16) & 1u)) >> 16;
    return (unsigned short)r;
}

static __device__ __forceinline__ unsigned int cvt_pk_bf16(float lo, float hi) {
    unsigned int d;
    asm volatile("v_cvt_pk_bf16_f32 %0, %1, %2" : "=v"(d) : "v"(lo), "v"(hi));
    return d;
}

// ---------------- prep: pack W into MFMA-B-fragment-linear Wfrag.
// idx = (cg*32 + kk)*512 + cl*32 + kq*8 + ke ; col = cg*16+cl (mat=col>>6), k = kk*32+kq*8+ke
// Coalesced linear READ of W, scattered 2B writes (fire-and-forget).
__global__ __launch_bounds__(256) void prep_kernel(
    const float* __restrict__ Wq, const float* __restrict__ Wk, const float* __restrict__ Wv,
    unsigned short* __restrict__ Wfrag)
{
    int j = blockIdx.x * 256 + threadIdx.x;     // 0 .. 196607
    int mat = j >> 16;
    int rem = j & 65535;
    int k = rem >> 6;
    int c = rem & 63;
    const float* W = (mat == 0) ? Wq : ((mat == 1) ? Wk : Wv);
    float v = W[rem];
    int col = mat * 64 + c;
    int cg = col >> 4, cl = col & 15;
    int kk = k >> 5, kq = (k >> 3) & 3, ke = k & 7;
    Wfrag[(size_t)(cg * 32 + kk) * 512 + cl * 32 + kq * 8 + ke] = f2bf(v);
}

// ---------------- QKV GEMM: X[16384x1024] fp32 -> Qb,Kb [16384x64] bf16, Vt [8][64][2048] bf16
// BM=16, 1024 blocks (4/CU), 2-deep X prefetch, cvt_pk conversions.
__global__ __launch_bounds__(256, 4) void qkv_kernel(
    const float* __restrict__ X, const unsigned short* __restrict__ Wfrag,
    const float* __restrict__ bq, const float* __restrict__ bk, const float* __restrict__ bv,
    unsigned short* __restrict__ Qb, unsigned short* __restrict__ Kb, unsigned short* __restrict__ Vt)
{
    __shared__ __align__(16) short As[16][128];   // 4 KiB, XOR-swizzled

    const int tid = threadIdx.x;
    const int w   = tid >> 6;
    const int l15 = tid & 15;
    const int lq  = (tid & 63) >> 4;
    const int row0 = blockIdx.x * 16;

    f32x4 acc[3] = {};

    const int srow = tid >> 4;            // 0..15
    const int scol = (tid & 15) * 8;      // float col within 128
    const float* xb = X + (size_t)(row0 + srow) * DIN + scol;
    const int swc = scol ^ ((srow & 7) << 3);   // swizzled short col

    const unsigned short* wfb[3];
    #pragma unroll
    for (int n = 0; n < 3; ++n)
        wfb[n] = Wfrag + (size_t)((w * 3 + n) * 32) * 512 + (l15 * 4 + lq) * 8;

    // 2-deep prefetch (compile-time reg selection under full unroll)
    float4 pa0 = *(const float4*)(xb);
    float4 pa1 = *(const float4*)(xb + 4);
    float4 pb0 = *(const float4*)(xb + 128);
    float4 pb1 = *(const float4*)(xb + 132);

    #pragma unroll
    for (int step = 0; step < 8; ++step) {
        float4 c0 = (step & 1) ? pb0 : pa0;
        float4 c1 = (step & 1) ? pb1 : pa1;
        unsigned int u0 = cvt_pk_bf16(c0.x, c0.y);
        unsigned int u1 = cvt_pk_bf16(c0.z, c0.w);
        unsigned int u2 = cvt_pk_bf16(c1.x, c1.y);
        unsigned int u3 = cvt_pk_bf16(c1.z, c1.w);

        if (step + 2 < 8) {
            const float* xn = xb + (step + 2) * 128;
            if (step & 1) { pb0 = *(const float4*)(xn); pb1 = *(const float4*)(xn + 4); }
            else          { pa0 = *(const float4*)(xn); pa1 = *(const float4*)(xn + 4); }
        }

        __syncthreads();
        uint4 pk; pk.x = u0; pk.y = u1; pk.z = u2; pk.w = u3;
        *(uint4*)&As[srow][swc] = pk;
        __syncthreads();

        #pragma unroll
        for (int kkl = 0; kkl < 4; ++kkl) {
            bf16x8 bfr[3];
            #pragma unroll
            for (int n = 0; n < 3; ++n)
                bfr[n] = *(const bf16x8*)(wfb[n] + (size_t)(step * 4 + kkl) * 512);
            bf16x8 a = *(const bf16x8*)&As[l15][(kkl * 32 + lq * 8) ^ ((l15 & 7) << 3)];
            #pragma unroll
            for (int n = 0; n < 3; ++n)
                acc[n] = __builtin_amdgcn_mfma_f32_16x16x32_bf16(a, bfr[n], acc[n], 0, 0, 0);
        }
    }

    // epilogue
    #pragma unroll
    for (int n = 0; n < 3; ++n) {
        int col = w * 48 + n * 16 + l15;
        int mat = col >> 6, c = col & 63;
        float badd = ((mat == 0) ? bq : ((mat == 1) ? bk : bv))[c];
        #pragma unroll
        for (int reg = 0; reg < 4; ++reg) {
            int row = row0 + lq * 4 + reg;
            unsigned short v16 = f2bf(acc[n][reg] + badd);
            if (mat == 0)      Qb[(size_t)row * DH + c] = v16;
            else if (mat == 1) Kb[(size_t)row * DH + c] = v16;
            else {
                int bb = row >> 11, ss = row & 2047;
                Vt[((size_t)(bb * DH + c)) * SEQ + ss] = v16;
            }
        }
    }
}

// ---------------- flash attention (fixed-max), QBLK=64, 512 threads / 8 waves.
// wave w: q-half wqh=w>>2 (32 rows), key-quarter wkq=w&3 (32 keys of each 128-key tile)
#define KT 128
#define NT (SEQ / KT)
#define PPITCH 36

__global__ __launch_bounds__(512, 2) void attn_kernel(
    const unsigned short* __restrict__ Qb, const unsigned short* __restrict__ Kb,
    const unsigned short* __restrict__ Vt, const int* __restrict__ mask,
    float* __restrict__ out)
{
    __shared__ __align__(16) unsigned char smem[65536 + 8 * 32 * PPITCH * 2 + 8 * 32 * 4];
    short (*Ks)[KT][DH]     = reinterpret_cast<short (*)[KT][DH]>(smem);           // [2][128][64]  32 KiB
    short (*Vs)[DH][KT]     = reinterpret_cast<short (*)[DH][KT]>(smem + 32768);   // [2][64][128]  32 KiB
    short (*ps)[32][PPITCH] = reinterpret_cast<short (*)[32][PPITCH]>(smem + 65536); // [8][32][36] 18 KiB
    float (*sml)[32]        = reinterpret_cast<float (*)[32]>(smem + 65536 + 8 * 32 * PPITCH * 2);
    float (*so)[64][64]     = reinterpret_cast<float (*)[64][64]>(smem);           // 64 KiB overlay (post-loop)

    const int tid = threadIdx.x;
    const int w   = tid >> 6;
    const int l   = tid & 63;
    const int l15 = l & 15;
    const int lq  = l >> 4;
    const int wqh = w >> 2;      // q-half
    const int wkq = w & 3;       // key-quarter

    int bid = blockIdx.x;
    bid = (bid & 7) * 32 + (bid >> 3);   // XCD swizzle: one batch per XCD (256 blocks, 32/batch)
    const int b  = bid >> 5;
    const int q0 = (bid & 31) * 64;

    // persistent Q fragments (2 m-frags x 2 kk) for this wave's 32 q-rows
    bf16x8 aq[2][2];
    #pragma unroll
    for (int m = 0; m < 2; ++m)
        #pragma unroll
        for (int kk = 0; kk < 2; ++kk)
            aq[m][kk] = *(const bf16x8*)(Qb + ((size_t)(b * SEQ + q0 + wqh * 32 + m * 16 + l15)) * DH + kk * 32 + lq * 8);

    // staging maps (512 threads)
    const int krow = tid >> 3;            // 0..63, +64 for second issue
    const int kcol = (tid & 7) * 8;       // short col in 64-wide K row
    const int kdst = kcol ^ ((krow & 7) << 3);
    const int vrow = tid >> 4;            // 0..31, +32 for second issue
    const int vcol = (tid & 15) * 8;      // short col in 128-wide V row
    const int vdst = vcol ^ ((vrow & 7) << 3);

    const unsigned short* Kbase = Kb + (size_t)(b * SEQ) * DH + kcol;
    const unsigned short* Vbase = Vt + (size_t)(b * DH) * SEQ + vcol;

    bf16x8 kr[2], vr[2];
    #pragma unroll
    for (int i = 0; i < 2; ++i) {
        kr[i] = *(const bf16x8*)(Kbase + (size_t)(i * 64 + krow) * DH);
        vr[i] = *(const bf16x8*)(Vbase + (size_t)(i * 32 + vrow) * SEQ);
    }

    f32x4 o[2][4];
    #pragma unroll
    for (int m = 0; m < 2; ++m)
        #pragma unroll
        for (int n = 0; n < 4; ++n) o[m][n] = f32x4{0, 0, 0, 0};
    float lr[2][4] = {};

    const float rscale = 0.022097086912079612f;  // 1/sqrt(2048)
    const int kw = wkq * 32;
    const int* mbase = mask + b * SEQ + kw + l15;

    for (int t = 0; t < NT; ++t) {
        const int cur = t & 1;

        // staged regs -> LDS (swizzled dest)
        #pragma unroll
        for (int i = 0; i < 2; ++i) *(bf16x8*)&Ks[cur][i * 64 + krow][kdst] = kr[i];
        #pragma unroll
        for (int i = 0; i < 2; ++i) *(bf16x8*)&Vs[cur][i * 32 + vrow][vdst] = vr[i];

        // mask bits for this tile (early issue, L2-resident)
        int mk0 = mbase[t * KT];
        int mk1 = mbase[t * KT + 16];

        // early-issue next tile's global loads
        if (t + 1 < NT) {
            const int key0n = (t + 1) * KT;
            #pragma unroll
            for (int i = 0; i < 2; ++i) {
                kr[i] = *(const bf16x8*)(Kbase + (size_t)(key0n + i * 64 + krow) * DH);
                vr[i] = *(const bf16x8*)(Vbase + (size_t)(i * 32 + vrow) * SEQ + key0n);
            }
        }

        __syncthreads();

        // ---- QK^T: 32 q-rows x 32 keys
        bf16x8 bkf[2][2];
        #pragma unroll
        for (int n = 0; n < 2; ++n)
            #pragma unroll
            for (int kk = 0; kk < 2; ++kk)
                bkf[n][kk] = *(const bf16x8*)&Ks[cur][kw + n * 16 + l15][(kk * 32 + lq * 8) ^ ((l15 & 7) << 3)];
        f32x4 s[2][2];
        #pragma unroll
        for (int m = 0; m < 2; ++m)
            #pragma unroll
            for (int n = 0; n < 2; ++n) s[m][n] = f32x4{0, 0, 0, 0};
        #pragma unroll
        for (int kk = 0; kk < 2; ++kk)
            #pragma unroll
            for (int m = 0; m < 2; ++m)
                #pragma unroll
                for (int n = 0; n < 2; ++n)
                    s[m][n] = __builtin_amdgcn_mfma_f32_16x16x32_bf16(aq[m][kk], bkf[n][kk], s[m][n], 0, 0, 0);

        // ---- p = exp(s*scale + maskbias); per-lane partial l; P -> ps (bf16)
        float bb0 = mk0 ? -1e30f : 0.0f;
        float bb1 = mk1 ? -1e30f : 0.0f;
        #pragma unroll
        for (int m = 0; m < 2; ++m)
            #pragma unroll
            for (int n = 0; n < 2; ++n) {
                float bvv = n ? bb1 : bb0;
                #pragma unroll
                for (int r = 0; r < 4; ++r) {
                    float p = __expf(fmaf(s[m][n][r], rscale, bvv));
                    lr[m][r] += p;
                    ps[w][m * 16 + lq * 4 + r][n * 16 + l15] = (short)f2bf(p);
                }
            }

        // ---- PV: P(32x32) x V(32x64)
        bf16x8 pa[2];
        #pragma unroll
        for (int m = 0; m < 2; ++m)
            pa[m] = *(const bf16x8*)&ps[w][m * 16 + l15][lq * 8];
        bf16x8 bvf[4];
        #pragma unroll
        for (int n = 0; n < 4; ++n)
            bvf[n] = *(const bf16x8*)&Vs[cur][n * 16 + l15][(kw + lq * 8) ^ ((l15 & 7) << 3)];
        #pragma unroll
        for (int m = 0; m < 2; ++m)
            #pragma unroll
            for (int n = 0; n < 4; ++n)
                o[m][n] = __builtin_amdgcn_mfma_f32_16x16x32_bf16(pa[m], bvf[n], o[m][n], 0, 0, 0);
    }

    // ---- reduce per-lane l partials across the 16 key-lanes
    #pragma unroll
    for (int off = 1; off < 16; off <<= 1)
        #pragma unroll
        for (int m = 0; m < 2; ++m)
            #pragma unroll
            for (int r = 0; r < 4; ++r) lr[m][r] += __shfl_xor(lr[m][r], off);
    if (l15 == 0) {
        #pragma unroll
        for (int m = 0; m < 2; ++m)
            #pragma unroll
            for (int r = 0; r < 4; ++r) sml[w][m * 16 + lq * 4 + r] = lr[m][r];
    }
    __syncthreads();   // all compute done; safe to overlay Ks/Vs with so

    #pragma unroll
    for (int m = 0; m < 2; ++m)
        #pragma unroll
        for (int n = 0; n < 4; ++n)
            #pragma unroll
            for (int r = 0; r < 4; ++r)
                so[wkq][wqh * 32 + m * 16 + lq * 4 + r][n * 16 + l15] = o[m][n][r];
    __syncthreads();

    // ---- final: sum the 4 key-quarters, normalize, store
    {
        int q  = tid >> 3;           // 0..63
        int d0 = (tid & 7) * 8;      // 0..56
        int wb = (q >> 5) * 4;
        float lt = sml[wb][q & 31] + sml[wb + 1][q & 31] + sml[wb + 2][q & 31] + sml[wb + 3][q & 31];
        float inv = 1.0f / lt;
        float vx[8];
        #pragma unroll
        for (int j = 0; j < 8; ++j)
            vx[j] = (so[0][q][d0 + j] + so[1][q][d0 + j] + so[2][q][d0 + j] + so[3][q][d0 + j]) * inv;
        float* op = out + ((size_t)(b * SEQ + q0 + q)) * DH + d0;
        float4 r0; r0.x = vx[0]; r0.y = vx[1]; r0.z = vx[2]; r0.w = vx[3];
        float4 r1; r1.x = vx[4]; r1.y = vx[5]; r1.z = vx[6]; r1.w = vx[7];
        *(float4*)op = r0;
        *(float4*)(op + 4) = r1;
    }
}

extern "C" void kernel_launch(void* const* d_in, const int* in_sizes, int n_in,
                              void* d_out, int out_size, void* d_ws, size_t ws_size,
                              hipStream_t stream) {
    const float* X    = (const float*)d_in[0];
    const int*   mask = (const int*)d_in[1];
    const float* Wq   = (const float*)d_in[2];
    const float* bq   = (const float*)d_in[3];
    const float* Wk   = (const float*)d_in[4];
    const float* bk   = (const float*)d_in[5];
    const float* Wv   = (const float*)d_in[6];
    const float* bv   = (const float*)d_in[7];
    float* out = (float*)d_out;

    char* ws = (char*)d_ws;
    unsigned short* Qb = (unsigned short*)(ws);                       // 2 MiB
    unsigned short* Kb = (unsigned short*)(ws + (2u << 20));          // 2 MiB
    unsigned short* Vt = (unsigned short*)(ws + (4u << 20));          // 2 MiB
    unsigned short* Wfrag = (unsigned short*)(ws + (6u << 20));       // 384 KiB

    prep_kernel<<<768, 256, 0, stream>>>(Wq, Wk, Wv, Wfrag);
    qkv_kernel<<<1024, 256, 0, stream>>>(X, Wfrag, bq, bk, bv, Qb, Kb, Vt);
    attn_kernel<<<256, 512, 0, stream>>>(Qb, Kb, Vt, mask, out);
}

// Round 5
// 60.472 us; speedup vs baseline: 1.1076x; 1.1076x over previous
//
#include <hip/hip_runtime.h>
#include <hip/hip_bf16.h>

#define NB 8
#define SEQ 2048
#define DIN 1024
#define DH 64

typedef __attribute__((ext_vector_type(8))) short bf16x8;
typedef __attribute__((ext_vector_type(4))) float f32x4;

static __device__ __forceinline__ unsigned short f2bf(float f) {
    unsigned int u = __builtin_bit_cast(unsigned int, f);
    unsigned int r = (u + 0x7FFFu + ((u >> 16) & 1u)) >> 16;
    return (unsigned short)r;
}

static __device__ __forceinline__ unsigned int cvt_pk_bf16(float lo, float hi) {
    unsigned int d;
    asm volatile("v_cvt_pk_bf16_f32 %0, %1, %2" : "=v"(d) : "v"(lo), "v"(hi));
    return d;
}

// ---------------- prep: pack W into MFMA-B-fragment-linear Wfrag.
// idx = (cg*32 + kk)*512 + cl*32 + kq*8 + ke ; col = cg*16+cl (mat=col>>6), k = kk*32+kq*8+ke
__global__ __launch_bounds__(256) void prep_kernel(
    const float* __restrict__ Wq, const float* __restrict__ Wk, const float* __restrict__ Wv,
    unsigned short* __restrict__ Wfrag)
{
    int j = blockIdx.x * 256 + threadIdx.x;     // 0 .. 196607
    int mat = j >> 16;
    int rem = j & 65535;
    int k = rem >> 6;
    int c = rem & 63;
    const float* W = (mat == 0) ? Wq : ((mat == 1) ? Wk : Wv);
    float v = W[rem];
    int col = mat * 64 + c;
    int cg = col >> 4, cl = col & 15;
    int kk = k >> 5, kq = (k >> 3) & 3, ke = k & 7;
    Wfrag[(size_t)(cg * 32 + kk) * 512 + cl * 32 + kq * 8 + ke] = f2bf(v);
}

// ---------------- QKV GEMM: BM=32, 512 blocks, dbuf LDS, 2-deep X prefetch,
// rolling 3-slot W-fragment register pipeline (6 MFMA per 3 W-loads).
__global__ __launch_bounds__(256, 2) void qkv_kernel(
    const float* __restrict__ X, const unsigned short* __restrict__ Wfrag,
    const float* __restrict__ bq, const float* __restrict__ bk, const float* __restrict__ bv,
    unsigned short* __restrict__ Qb, unsigned short* __restrict__ Kb, unsigned short* __restrict__ Vt)
{
    __shared__ __align__(16) short As[2][32][128];   // 16 KiB, XOR-swizzled (16B granules)

    const int tid = threadIdx.x;
    const int w   = tid >> 6;
    const int l   = tid & 63;
    const int l15 = l & 15;
    const int lq  = l >> 4;
    const int row0 = blockIdx.x * 32;

    f32x4 acc[2][3] = {};

    const float* xb = X + (size_t)row0 * DIN;

    const unsigned short* wfb[3];
    #pragma unroll
    for (int n = 0; n < 3; ++n)
        wfb[n] = Wfrag + (size_t)((w * 3 + n) * 32) * 512 + (l15 * 4 + lq) * 8;

    // ---- X prefetch, 2 steps deep; flat chunk c -> row c>>5, float4-col c&31 (coalesced)
    float4 pf[2][4];
    #pragma unroll
    for (int i = 0; i < 4; ++i) {
        int c = tid + 256 * i;
        const float* p = xb + (size_t)(c >> 5) * DIN + (c & 31) * 4;
        pf[0][i] = *(const float4*)(p);
        pf[1][i] = *(const float4*)(p + 128);
    }

    // ---- W rolling prefetch (slots mod 3, 2-chunk lookahead)
    bf16x8 wb[3][3];
    #pragma unroll
    for (int n = 0; n < 3; ++n) wb[0][n] = *(const bf16x8*)(wfb[n]);
    #pragma unroll
    for (int n = 0; n < 3; ++n) wb[1][n] = *(const bf16x8*)(wfb[n] + 512);

    #pragma unroll
    for (int step = 0; step < 8; ++step) {
        const int pi = step & 1;

        // convert this step's 16 floats -> 8 packed bf16 pairs
        unsigned int u[8];
        #pragma unroll
        for (int i = 0; i < 4; ++i) {
            u[2 * i]     = cvt_pk_bf16(pf[pi][i].x, pf[pi][i].y);
            u[2 * i + 1] = cvt_pk_bf16(pf[pi][i].z, pf[pi][i].w);
        }
        // write to LDS buf[pi], 8B pieces, swizzled 16B granules
        #pragma unroll
        for (int i = 0; i < 4; ++i) {
            int c = tid + 256 * i;
            int r = c >> 5;
            int bo = ((c & 31) * 8) ^ ((r & 7) << 4);
            uint2 v2; v2.x = u[2 * i]; v2.y = u[2 * i + 1];
            *(uint2*)((char*)&As[pi][r][0] + bo) = v2;
        }
        // prefetch step+2 into the just-freed slot
        if (step + 2 < 8) {
            #pragma unroll
            for (int i = 0; i < 4; ++i) {
                int c = tid + 256 * i;
                pf[pi][i] = *(const float4*)(xb + (size_t)(c >> 5) * DIN + (step + 2) * 128 + (c & 31) * 4);
            }
        }
        __syncthreads();

        #pragma unroll
        for (int kkl = 0; kkl < 4; ++kkl) {
            const int c = step * 4 + kkl;
            if (c + 2 < 32) {
                #pragma unroll
                for (int n = 0; n < 3; ++n)
                    wb[(c + 2) % 3][n] = *(const bf16x8*)(wfb[n] + (size_t)(c + 2) * 512);
            }
            bf16x8 a[2];
            #pragma unroll
            for (int m = 0; m < 2; ++m) {
                int r = m * 16 + l15;
                int bo = ((kkl * 32 + lq * 8) * 2) ^ ((r & 7) << 4);
                a[m] = *(const bf16x8*)((const char*)&As[pi][r][0] + bo);
            }
            #pragma unroll
            for (int m = 0; m < 2; ++m)
                #pragma unroll
                for (int n = 0; n < 3; ++n)
                    acc[m][n] = __builtin_amdgcn_mfma_f32_16x16x32_bf16(a[m], wb[c % 3][n], acc[m][n], 0, 0, 0);
        }
    }

    // epilogue
    #pragma unroll
    for (int n = 0; n < 3; ++n) {
        int col = w * 48 + n * 16 + l15;
        int mat = col >> 6, c = col & 63;
        float badd = ((mat == 0) ? bq : ((mat == 1) ? bk : bv))[c];
        #pragma unroll
        for (int m = 0; m < 2; ++m) {
            #pragma unroll
            for (int reg = 0; reg < 4; ++reg) {
                int row = row0 + m * 16 + lq * 4 + reg;
                unsigned short v16 = f2bf(acc[m][n][reg] + badd);
                if (mat == 0)      Qb[(size_t)row * DH + c] = v16;
                else if (mat == 1) Kb[(size_t)row * DH + c] = v16;
                else {
                    int bb = row >> 11, ss = row & 2047;
                    Vt[((size_t)(bb * DH + c)) * SEQ + ss] = v16;
                }
            }
        }
    }
}

// ---------------- flash attention (fixed-max), QBLK=64, 512 threads / 8 waves,
// single-buffered K/V (LDS 51 KiB -> 2+ blocks/CU), in-place f32 merge overlay.
#define KT 128
#define NT (SEQ / KT)
#define PPITCH 36

__global__ __launch_bounds__(512, 4) void attn_kernel(
    const unsigned short* __restrict__ Qb, const unsigned short* __restrict__ Kb,
    const unsigned short* __restrict__ Vt, const int* __restrict__ mask,
    float* __restrict__ out)
{
    __shared__ __align__(16) unsigned char smem[32768 + 8 * 32 * PPITCH * 2 + 8 * 32 * 4];
    short (*Ks)[DH]         = reinterpret_cast<short (*)[DH]>(smem);                 // [128][64] 16 KiB
    short (*Vs)[KT]         = reinterpret_cast<short (*)[KT]>(smem + 16384);         // [64][128] 16 KiB
    short (*ps)[32][PPITCH] = reinterpret_cast<short (*)[32][PPITCH]>(smem + 32768); // [8][32][36] 18 KiB
    float (*sml)[32]        = reinterpret_cast<float (*)[32]>(smem + 32768 + 8 * 32 * PPITCH * 2);
    float (*Om)[68]         = reinterpret_cast<float (*)[68]>(smem);                 // [64][68] 17 KiB overlay

    const int tid = threadIdx.x;
    const int w   = tid >> 6;
    const int l   = tid & 63;
    const int l15 = l & 15;
    const int lq  = l >> 4;
    const int wqh = w >> 2;      // q-half
    const int wkq = w & 3;       // key-quarter

    int bid = blockIdx.x;
    bid = (bid & 7) * 32 + (bid >> 3);   // XCD swizzle: one batch per XCD
    const int b  = bid >> 5;
    const int q0 = (bid & 31) * 64;

    // persistent Q fragments
    bf16x8 aq[2][2];
    #pragma unroll
    for (int m = 0; m < 2; ++m)
        #pragma unroll
        for (int kk = 0; kk < 2; ++kk)
            aq[m][kk] = *(const bf16x8*)(Qb + ((size_t)(b * SEQ + q0 + wqh * 32 + m * 16 + l15)) * DH + kk * 32 + lq * 8);

    // staging maps (512 threads)
    const int krow = tid >> 3;            // 0..63 (+64 second issue)
    const int kcol = (tid & 7) * 8;       // short col in 64-wide K row
    const int kdst = kcol ^ ((krow & 7) << 3);
    const int vrow = tid >> 4;            // 0..31 (+32 second issue)
    const int vcol = (tid & 15) * 8;      // short col in 128-wide V row
    const int vdst = vcol ^ ((vrow & 7) << 3);

    const unsigned short* Kbase = Kb + (size_t)(b * SEQ) * DH + kcol;
    const unsigned short* Vbase = Vt + (size_t)(b * DH) * SEQ + vcol;

    bf16x8 kr[2], vr[2];
    #pragma unroll
    for (int i = 0; i < 2; ++i) {
        kr[i] = *(const bf16x8*)(Kbase + (size_t)(i * 64 + krow) * DH);
        vr[i] = *(const bf16x8*)(Vbase + (size_t)(i * 32 + vrow) * SEQ);
    }

    f32x4 o[2][4];
    #pragma unroll
    for (int m = 0; m < 2; ++m)
        #pragma unroll
        for (int n = 0; n < 4; ++n) o[m][n] = f32x4{0, 0, 0, 0};
    float lr[2][4] = {};

    const float rscale = 0.022097086912079612f;  // 1/sqrt(2048)
    const int kw = wkq * 32;
    const int* mbase = mask + b * SEQ + kw + l15;

    for (int t = 0; t < NT; ++t) {
        // staged regs -> LDS (swizzled dest)
        #pragma unroll
        for (int i = 0; i < 2; ++i) *(bf16x8*)&Ks[i * 64 + krow][kdst] = kr[i];
        #pragma unroll
        for (int i = 0; i < 2; ++i) *(bf16x8*)&Vs[i * 32 + vrow][vdst] = vr[i];

        int mk0 = mbase[t * KT];
        int mk1 = mbase[t * KT + 16];

        // early-issue next tile's global loads (cover = full compute phase)
        if (t + 1 < NT) {
            const int key0n = (t + 1) * KT;
            #pragma unroll
            for (int i = 0; i < 2; ++i) {
                kr[i] = *(const bf16x8*)(Kbase + (size_t)(key0n + i * 64 + krow) * DH);
                vr[i] = *(const bf16x8*)(Vbase + (size_t)(i * 32 + vrow) * SEQ + key0n);
            }
        }

        __syncthreads();   // LDS tile ready

        // ---- QK^T: 32 q-rows x 32 keys
        bf16x8 bkf[2][2];
        #pragma unroll
        for (int n = 0; n < 2; ++n)
            #pragma unroll
            for (int kk = 0; kk < 2; ++kk)
                bkf[n][kk] = *(const bf16x8*)&Ks[kw + n * 16 + l15][(kk * 32 + lq * 8) ^ ((l15 & 7) << 3)];
        f32x4 s[2][2];
        #pragma unroll
        for (int m = 0; m < 2; ++m)
            #pragma unroll
            for (int n = 0; n < 2; ++n) s[m][n] = f32x4{0, 0, 0, 0};
        #pragma unroll
        for (int kk = 0; kk < 2; ++kk)
            #pragma unroll
            for (int m = 0; m < 2; ++m)
                #pragma unroll
                for (int n = 0; n < 2; ++n)
                    s[m][n] = __builtin_amdgcn_mfma_f32_16x16x32_bf16(aq[m][kk], bkf[n][kk], s[m][n], 0, 0, 0);

        // ---- p = exp(s*scale + maskbias); per-lane partial l; P -> ps
        float bb0 = mk0 ? -1e30f : 0.0f;
        float bb1 = mk1 ? -1e30f : 0.0f;
        #pragma unroll
        for (int m = 0; m < 2; ++m)
            #pragma unroll
            for (int n = 0; n < 2; ++n) {
                float bvv = n ? bb1 : bb0;
                #pragma unroll
                for (int r = 0; r < 4; ++r) {
                    float p = __expf(fmaf(s[m][n][r], rscale, bvv));
                    lr[m][r] += p;
                    ps[w][m * 16 + lq * 4 + r][n * 16 + l15] = (short)f2bf(p);
                }
            }

        // ---- PV: P(32x32) x V(32x64)
        bf16x8 pa[2];
        #pragma unroll
        for (int m = 0; m < 2; ++m)
            pa[m] = *(const bf16x8*)&ps[w][m * 16 + l15][lq * 8];
        bf16x8 bvf[4];
        #pragma unroll
        for (int n = 0; n < 4; ++n)
            bvf[n] = *(const bf16x8*)&Vs[n * 16 + l15][(kw + lq * 8) ^ ((l15 & 7) << 3)];
        #pragma unroll
        for (int m = 0; m < 2; ++m)
            #pragma unroll
            for (int n = 0; n < 4; ++n)
                o[m][n] = __builtin_amdgcn_mfma_f32_16x16x32_bf16(pa[m], bvf[n], o[m][n], 0, 0, 0);

        __syncthreads();   // all reads done; next iter may overwrite K/V
    }

    // ---- l: reduce per-lane partials across the 16 key-lanes
    #pragma unroll
    for (int off = 1; off < 16; off <<= 1)
        #pragma unroll
        for (int m = 0; m < 2; ++m)
            #pragma unroll
            for (int r = 0; r < 4; ++r) lr[m][r] += __shfl_xor(lr[m][r], off);
    if (l15 == 0) {
        #pragma unroll
        for (int m = 0; m < 2; ++m)
            #pragma unroll
            for (int r = 0; r < 4; ++r) sml[w][m * 16 + lq * 4 + r] = lr[m][r];
    }

    // ---- in-place merge of the 4 key-quarters through Om overlay (rounds by wkq)
    #pragma unroll
    for (int rnd = 0; rnd < 4; ++rnd) {
        __syncthreads();
        if (wkq == rnd) {
            #pragma unroll
            for (int m = 0; m < 2; ++m)
                #pragma unroll
                for (int n = 0; n < 4; ++n)
                    #pragma unroll
                    for (int r = 0; r < 4; ++r) {
                        int row = wqh * 32 + m * 16 + lq * 4 + r;
                        int col = n * 16 + l15;
                        if (rnd == 0) Om[row][col] = o[m][n][r];
                        else          Om[row][col] += o[m][n][r];
                    }
        }
    }
    __syncthreads();

    // ---- final: normalize, store
    {
        int q  = tid >> 3;           // 0..63
        int d0 = (tid & 7) * 8;      // 0..56
        int wb = (q >> 5) * 4;
        float lt = sml[wb][q & 31] + sml[wb + 1][q & 31] + sml[wb + 2][q & 31] + sml[wb + 3][q & 31];
        float inv = 1.0f / lt;
        float vx[8];
        #pragma unroll
        for (int j = 0; j < 8; ++j) vx[j] = Om[q][d0 + j] * inv;
        float* op = out + ((size_t)(b * SEQ + q0 + q)) * DH + d0;
        float4 r0; r0.x = vx[0]; r0.y = vx[1]; r0.z = vx[2]; r0.w = vx[3];
        float4 r1; r1.x = vx[4]; r1.y = vx[5]; r1.z = vx[6]; r1.w = vx[7];
        *(float4*)op = r0;
        *(float4*)(op + 4) = r1;
    }
}

extern "C" void kernel_launch(void* const* d_in, const int* in_sizes, int n_in,
                              void* d_out, int out_size, void* d_ws, size_t ws_size,
                              hipStream_t stream) {
    const float* X    = (const float*)d_in[0];
    const int*   mask = (const int*)d_in[1];
    const float* Wq   = (const float*)d_in[2];
    const float* bq   = (const float*)d_in[3];
    const float* Wk   = (const float*)d_in[4];
    const float* bk   = (const float*)d_in[5];
    const float* Wv   = (const float*)d_in[6];
    const float* bv   = (const float*)d_in[7];
    float* out = (float*)d_out;

    char* ws = (char*)d_ws;
    unsigned short* Qb = (unsigned short*)(ws);                       // 2 MiB
    unsigned short* Kb = (unsigned short*)(ws + (2u << 20));          // 2 MiB
    unsigned short* Vt = (unsigned short*)(ws + (4u << 20));          // 2 MiB
    unsigned short* Wfrag = (unsigned short*)(ws + (6u << 20));       // 384 KiB

    prep_kernel<<<768, 256, 0, stream>>>(Wq, Wk, Wv, Wfrag);
    qkv_kernel<<<512, 256, 0, stream>>>(X, Wfrag, bq, bk, bv, Qb, Kb, Vt);
    attn_kernel<<<256, 512, 0, stream>>>(Qb, Kb, Vt, mask, out);
}